// Round 5
// baseline (145.194 us; speedup 1.0000x reference)
//
#include <hip/hip_runtime.h>
#include <math.h>

// Problem constants: N=128, LQ=LK=64, D=512, H=8 (head split is a no-op in the einsum).
#define DN 512          // feature dim
#define NB 128          // batch N

typedef unsigned short ushort_t;
typedef __attribute__((ext_vector_type(8))) short bf16x8;
typedef __attribute__((ext_vector_type(4))) float f32x4;

static __device__ __forceinline__ ushort_t f2bf(float f){
  unsigned u = __float_as_uint(f);
  u += 0x7fffu + ((u >> 16) & 1u);   // round-to-nearest-even
  return (ushort_t)(u >> 16);
}

// async global->LDS, 16B per lane; LDS dest is wave-uniform base + lane*16
#define GLL16(gp, lp)                                                          \
  __builtin_amdgcn_global_load_lds(                                            \
      (const __attribute__((address_space(1))) void*)(gp),                     \
      (__attribute__((address_space(3))) void*)(lp), 16, 0, 0)

#define BAR() __builtin_amdgcn_s_barrier()
#define SCHED0() __builtin_amdgcn_sched_barrier(0)
#define VMC(N)                                                                 \
  do {                                                                         \
    asm volatile("s_waitcnt vmcnt(" #N ")" ::: "memory");                      \
  } while (0)

// ---------------------------------------------------------------------------
// Projections (both Q and K in one launch; z selects). Out = X @ W^T + bias,
// 128x128 tile, BK=64, 4 waves. LDS uses 16B-slot XOR swizzle (slot ^= row&7).
__global__ __launch_bounds__(256) void proj_kernel(const float* __restrict__ Xq,
                                                   const float* __restrict__ Wq,
                                                   const float* __restrict__ bq,
                                                   ushort_t* __restrict__ Oq,
                                                   const float* __restrict__ Xk,
                                                   const float* __restrict__ Wk,
                                                   const float* __restrict__ bk,
                                                   ushort_t* __restrict__ Ok) {
  const float* X = blockIdx.z ? Xk : Xq;
  const float* W = blockIdx.z ? Wk : Wq;
  const float* bias = blockIdx.z ? bk : bq;
  ushort_t* Out = blockIdx.z ? Ok : Oq;

  __shared__ __align__(16) ushort_t As[128 * 64];
  __shared__ __align__(16) ushort_t Bs[128 * 64];
  const int tid = threadIdx.x;
  const int wave = tid >> 6, lane = tid & 63;
  const int wr = wave >> 1, wc = wave & 1;
  const int m0 = blockIdx.y * 128, n0 = blockIdx.x * 128;
  const int arow = lane & 15, g = lane >> 4;

  f32x4 acc[4][4] = {};

  for (int kt = 0; kt < 8; ++kt) {
    const int k0 = kt * 64;
#pragma unroll
    for (int i = 0; i < 8; i++) {
      int e = i * 1024 + tid * 4;
      int r = e >> 6, c = e & 63;
      int cs = ((((c >> 3) ^ (r & 7)) << 3) | (c & 7));
      float4 va = *(const float4*)&X[(size_t)(m0 + r) * DN + k0 + c];
      ushort4 ha;
      ha.x = f2bf(va.x); ha.y = f2bf(va.y); ha.z = f2bf(va.z); ha.w = f2bf(va.w);
      *(ushort4*)&As[r * 64 + cs] = ha;
      float4 vb = *(const float4*)&W[(size_t)(n0 + r) * DN + k0 + c];
      ushort4 hb;
      hb.x = f2bf(vb.x); hb.y = f2bf(vb.y); hb.z = f2bf(vb.z); hb.w = f2bf(vb.w);
      *(ushort4*)&Bs[r * 64 + cs] = hb;
    }
    __syncthreads();

    bf16x8 af[4][2], bfr[4][2];
#pragma unroll
    for (int mi = 0; mi < 4; mi++)
#pragma unroll
      for (int ks = 0; ks < 2; ks++)
        af[mi][ks] = *(const bf16x8*)&As[(wr * 64 + mi * 16 + arow) * 64 +
                                         ((((ks << 2) | g) ^ (arow & 7)) << 3)];
#pragma unroll
    for (int ni = 0; ni < 4; ni++)
#pragma unroll
      for (int ks = 0; ks < 2; ks++)
        bfr[ni][ks] = *(const bf16x8*)&Bs[(wc * 64 + ni * 16 + arow) * 64 +
                                          ((((ks << 2) | g) ^ (arow & 7)) << 3)];
#pragma unroll
    for (int ks = 0; ks < 2; ks++)
#pragma unroll
      for (int mi = 0; mi < 4; mi++)
#pragma unroll
        for (int ni = 0; ni < 4; ni++)
          acc[mi][ni] = __builtin_amdgcn_mfma_f32_16x16x32_bf16(
              af[mi][ks], bfr[ni][ks], acc[mi][ni], 0, 0, 0);
    __syncthreads();
  }

  float bc[4];
#pragma unroll
  for (int ni = 0; ni < 4; ni++) bc[ni] = bias[n0 + wc * 64 + ni * 16 + arow];
#pragma unroll
  for (int mi = 0; mi < 4; mi++)
#pragma unroll
    for (int ni = 0; ni < 4; ni++)
#pragma unroll
      for (int j = 0; j < 4; j++) {
        int row = m0 + wr * 64 + mi * 16 + (lane >> 4) * 4 + j;
        int col = n0 + wc * 64 + ni * 16 + arow;
        Out[(size_t)row * DN + col] = f2bf(acc[mi][ni][j] + bc[ni]);
      }
}

// ---------------------------------------------------------------------------
// Pairwise logits + fused max/sum reductions. One 256x256 output tile per
// block (4 a's x 4 b's). 16 waves (4M x 4N), per-wave output 64x64 = exactly
// one (a,b) pair; acc = 64 regs -> ~120 total -> 4 waves/SIMD (the round-5
// lever: 2x the independent streams per SIMD to cover LDS/stage latency).
// K-loop: 8 tiles of BK=64, double-buffered LDS, one barrier per tile,
// counted per-wave vmcnt (1 gll16 per wave per stage unit).
// XCD-rectangle block swizzle: 4x8 (by,bx) rectangle per XCD per generation.
__global__ __launch_bounds__(1024) void pairs_kernel(const ushort_t* __restrict__ Q,
                                                     const ushort_t* __restrict__ Km,
                                                     const float* __restrict__ amask,
                                                     const float* __restrict__ ls_ptr,
                                                     float* __restrict__ out) {
  __shared__ __align__(16) ushort_t lds[2 * 2 * 256 * 64];  // 128 KiB
  const int tid = threadIdx.x;
  const int wave = tid >> 6, lane = tid & 63;
  const int wr = wave >> 2, wc = wave & 3;      // 4M x 4N wave grid
  const int arow = lane & 15, g = lane >> 4;

  const int bid = blockIdx.x;
  const int gen = bid >> 8, slot = bid & 255;
  const int xcd = slot & 7, idx = slot >> 3;
  const int by = ((gen & 1) << 4) + ((xcd >> 1) << 2) + (idx >> 3);
  const int bx = ((gen >> 1) << 4) + ((xcd & 1) << 3) + (idx & 7);

  const int l8 = lane >> 3, l7 = lane & 7;
  const int srcSlot = l7 ^ l8;

  // epilogue scalars first; drain their vmem so pipeline vmcnt counts are exact
  const float lsv = expf(ls_ptr[0]);
  float amv;
  {
    float am = amask[(by * 4 + wr) * 64 + lane];
#pragma unroll
    for (int off = 1; off < 64; off <<= 1) am += __shfl_xor(am, off);
    amv = am;
  }
  VMC(0); SCHED0();

  f32x4 acc[4][4] = {};
  bf16x8 aF[2][2], bR0[4], bR1[4];

  // Stage units (1 gll16 per wave each):
  //  A-u0: rows r with (r&32)==0; A-u1: (r&32)==32; B-lo: rows 0-127; B-hi: 128-255.
  auto SA = [&](int u, int k, int d) {
    int row = wr * 64 + wc * 8 + u * 32;                      // wave-uniform
    GLL16(Q + (size_t)(by * 256 + row + l8) * DN + k * 64 + srcSlot * 8,
          &lds[((d * 2 + 0) * 256 + row) * 64]);
  };
  auto SB = [&](int half, int k, int d) {
    int row = half * 128 + wave * 8;
    GLL16(Km + (size_t)(bx * 256 + row + l8) * DN + k * 64 + srcSlot * 8,
          &lds[((d * 2 + 1) * 256 + row) * 64]);
  };
  auto LDB = [&](bf16x8* br, int ks, int d) {
#pragma unroll
    for (int ni = 0; ni < 4; ni++) {
      int row = wc * 64 + ni * 16 + arow;
      int slt = ((ks << 2) | g) ^ (arow & 7);
      br[ni] = *(const bf16x8*)&lds[((d * 2 + 1) * 256 + row) * 64 + slt * 8];
    }
  };
  auto LDA = [&](int mh, int d) {
#pragma unroll
    for (int mi = 0; mi < 2; mi++)
#pragma unroll
      for (int ks = 0; ks < 2; ks++) {
        int row = wr * 64 + (mh * 2 + mi) * 16 + arow;
        int slt = ((ks << 2) | g) ^ (arow & 7);
        aF[mi][ks] = *(const bf16x8*)&lds[((d * 2 + 0) * 256 + row) * 64 + slt * 8];
      }
  };
  auto MMA = [&](int mh) {
    __builtin_amdgcn_s_setprio(1);
#pragma unroll
    for (int ks = 0; ks < 2; ks++)
#pragma unroll
      for (int mi = 0; mi < 2; mi++)
#pragma unroll
        for (int ni = 0; ni < 4; ni++)
          acc[mh * 2 + mi][ni] = __builtin_amdgcn_mfma_f32_16x16x32_bf16(
              aF[mi][ks], ks ? bR1[ni] : bR0[ni], acc[mh * 2 + mi][ni], 0, 0, 0);
    __builtin_amdgcn_s_setprio(0);
  };

  // prologue: stage tile 0; wait {B-lo,B-hi,A-u0}, leave A-u1 in flight
  SB(0, 0, 0); SB(1, 0, 0); SA(0, 0, 0); SA(1, 0, 0);
  VMC(1);
  BAR(); SCHED0();

#pragma unroll
  for (int k = 0; k < 8; ++k) {
    const int d = k & 1, dn = d ^ 1;
    const bool doST = (k < 7);
    // issue next tile's 4 stage loads first (issue-early, land-late)
    if (doST) { SB(0, k + 1, dn); SB(1, k + 1, dn); SA(0, k + 1, dn); SA(1, k + 1, dn); }
    LDB(bR0, 0, d); LDB(bR1, 1, d);
    LDA(0, d); MMA(0);                      // rows in A-u0 (validated at boundary)
    if (doST) { VMC(4); } else { VMC(0); }  // validate THIS tile's A-u1
    LDA(1, d); MMA(1);
    if (doST) { VMC(1); }                   // next tile's {B-lo,B-hi,A-u0} landed
    BAR(); SCHED0();
  }

  // ---- fused epilogue: one (a,b) pair per wave ----
  // C/D layout: col = lane&15, row = (lane>>4)*4 + reg.
  float t2v = 0.f;
#pragma unroll
  for (int mi = 0; mi < 4; mi++) {
    f32x4 rm = acc[mi][0];
#pragma unroll
    for (int ni = 1; ni < 4; ni++)
#pragma unroll
      for (int j = 0; j < 4; j++) rm[j] = fmaxf(rm[j], acc[mi][ni][j]);
#pragma unroll
    for (int off = 1; off < 16; off <<= 1)
#pragma unroll
      for (int j = 0; j < 4; j++) rm[j] = fmaxf(rm[j], __shfl_xor(rm[j], off));
    t2v += rm[0] + rm[1] + rm[2] + rm[3];
  }
  t2v += __shfl_xor(t2v, 16);
  t2v += __shfl_xor(t2v, 32);

  float v2t = 0.f;
#pragma unroll
  for (int ni = 0; ni < 4; ni++) {
    float cm = -INFINITY;
#pragma unroll
    for (int mi = 0; mi < 4; mi++)
#pragma unroll
      for (int j = 0; j < 4; j++) cm = fmaxf(cm, acc[mi][ni][j]);
    cm = fmaxf(cm, __shfl_xor(cm, 16));
    cm = fmaxf(cm, __shfl_xor(cm, 32));
    v2t += cm;
  }
#pragma unroll
  for (int off = 1; off < 16; off <<= 1) v2t += __shfl_xor(v2t, off);

  const int a = by * 4 + wr, b = bx * 4 + wc;
  float r = lsv * 0.5f * (t2v / amv + v2t / 64.0f);
  if (lane == 0) {
    out[a * NB + b] = r;                 // r
    out[NB * NB + b * NB + a] = r;       // r.T
  }
}

// ---------------------------------------------------------------------------
extern "C" void kernel_launch(void* const* d_in, const int* in_sizes, int n_in,
                              void* d_out, int out_size, void* d_ws, size_t ws_size,
                              hipStream_t stream) {
  const float* query = (const float*)d_in[0];
  const float* key   = (const float*)d_in[1];
  const float* amask = (const float*)d_in[2];
  const float* Wq    = (const float*)d_in[3];
  const float* bq    = (const float*)d_in[4];
  const float* Wk    = (const float*)d_in[5];
  const float* bk    = (const float*)d_in[6];
  const float* ls    = (const float*)d_in[7];

  char* ws = (char*)d_ws;
  ushort_t* Qb = (ushort_t*)(ws);                      // 8 MB
  ushort_t* Kb = (ushort_t*)(ws + 8 * 1024 * 1024);    // 8 MB

  proj_kernel<<<dim3(4, 64, 2), 256, 0, stream>>>(query, Wq, bq, Qb, key, Wk, bk, Kb);
  pairs_kernel<<<dim3(1024), 1024, 0, stream>>>(Qb, Kb, amask, ls, (float*)d_out);
}

// Round 6
// 123.815 us; speedup vs baseline: 1.1727x; 1.1727x over previous
//
#include <hip/hip_runtime.h>
#include <math.h>

// Problem constants: N=128, LQ=LK=64, D=512, H=8 (head split is a no-op in the einsum).
#define DN 512          // feature dim
#define NB 128          // batch N

typedef unsigned short ushort_t;
typedef __attribute__((ext_vector_type(8))) short bf16x8;
typedef __attribute__((ext_vector_type(4))) float f32x4;
typedef __attribute__((ext_vector_type(16))) float f32x16;

static __device__ __forceinline__ ushort_t f2bf(float f){
  unsigned u = __float_as_uint(f);
  u += 0x7fffu + ((u >> 16) & 1u);   // round-to-nearest-even
  return (ushort_t)(u >> 16);
}

// async global->LDS, 16B per lane; LDS dest is wave-uniform base + lane*16
#define GLL16(gp, lp)                                                          \
  __builtin_amdgcn_global_load_lds(                                            \
      (const __attribute__((address_space(1))) void*)(gp),                     \
      (__attribute__((address_space(3))) void*)(lp), 16, 0, 0)

#define BAR() __builtin_amdgcn_s_barrier()
#define SCHED0() __builtin_amdgcn_sched_barrier(0)
#define VMC(N)                                                                 \
  do {                                                                         \
    asm volatile("s_waitcnt vmcnt(" #N ")" ::: "memory");                      \
  } while (0)

// ---------------------------------------------------------------------------
// Projections (both Q and K in one launch; z selects). Out = X @ W^T + bias,
// 128x128 tile, BK=64, 4 waves. LDS uses 16B-slot XOR swizzle (slot ^= row&7).
__global__ __launch_bounds__(256) void proj_kernel(const float* __restrict__ Xq,
                                                   const float* __restrict__ Wq,
                                                   const float* __restrict__ bq,
                                                   ushort_t* __restrict__ Oq,
                                                   const float* __restrict__ Xk,
                                                   const float* __restrict__ Wk,
                                                   const float* __restrict__ bk,
                                                   ushort_t* __restrict__ Ok) {
  const float* X = blockIdx.z ? Xk : Xq;
  const float* W = blockIdx.z ? Wk : Wq;
  const float* bias = blockIdx.z ? bk : bq;
  ushort_t* Out = blockIdx.z ? Ok : Oq;

  __shared__ __align__(16) ushort_t As[128 * 64];
  __shared__ __align__(16) ushort_t Bs[128 * 64];
  const int tid = threadIdx.x;
  const int wave = tid >> 6, lane = tid & 63;
  const int wr = wave >> 1, wc = wave & 1;
  const int m0 = blockIdx.y * 128, n0 = blockIdx.x * 128;
  const int arow = lane & 15, g = lane >> 4;

  f32x4 acc[4][4] = {};

  for (int kt = 0; kt < 8; ++kt) {
    const int k0 = kt * 64;
#pragma unroll
    for (int i = 0; i < 8; i++) {
      int e = i * 1024 + tid * 4;
      int r = e >> 6, c = e & 63;
      int cs = ((((c >> 3) ^ (r & 7)) << 3) | (c & 7));
      float4 va = *(const float4*)&X[(size_t)(m0 + r) * DN + k0 + c];
      ushort4 ha;
      ha.x = f2bf(va.x); ha.y = f2bf(va.y); ha.z = f2bf(va.z); ha.w = f2bf(va.w);
      *(ushort4*)&As[r * 64 + cs] = ha;
      float4 vb = *(const float4*)&W[(size_t)(n0 + r) * DN + k0 + c];
      ushort4 hb;
      hb.x = f2bf(vb.x); hb.y = f2bf(vb.y); hb.z = f2bf(vb.z); hb.w = f2bf(vb.w);
      *(ushort4*)&Bs[r * 64 + cs] = hb;
    }
    __syncthreads();

    bf16x8 af[4][2], bfr[4][2];
#pragma unroll
    for (int mi = 0; mi < 4; mi++)
#pragma unroll
      for (int ks = 0; ks < 2; ks++)
        af[mi][ks] = *(const bf16x8*)&As[(wr * 64 + mi * 16 + arow) * 64 +
                                         ((((ks << 2) | g) ^ (arow & 7)) << 3)];
#pragma unroll
    for (int ni = 0; ni < 4; ni++)
#pragma unroll
      for (int ks = 0; ks < 2; ks++)
        bfr[ni][ks] = *(const bf16x8*)&Bs[(wc * 64 + ni * 16 + arow) * 64 +
                                          ((((ks << 2) | g) ^ (arow & 7)) << 3)];
#pragma unroll
    for (int ks = 0; ks < 2; ks++)
#pragma unroll
      for (int mi = 0; mi < 4; mi++)
#pragma unroll
        for (int ni = 0; ni < 4; ni++)
          acc[mi][ni] = __builtin_amdgcn_mfma_f32_16x16x32_bf16(
              af[mi][ks], bfr[ni][ks], acc[mi][ni], 0, 0, 0);
    __syncthreads();
  }

  float bc[4];
#pragma unroll
  for (int ni = 0; ni < 4; ni++) bc[ni] = bias[n0 + wc * 64 + ni * 16 + arow];
#pragma unroll
  for (int mi = 0; mi < 4; mi++)
#pragma unroll
    for (int ni = 0; ni < 4; ni++)
#pragma unroll
      for (int j = 0; j < 4; j++) {
        int row = m0 + wr * 64 + mi * 16 + (lane >> 4) * 4 + j;
        int col = n0 + wc * 64 + ni * 16 + arow;
        Out[(size_t)row * DN + col] = f2bf(acc[mi][ni][j] + bc[ni]);
      }
}

// ---------------------------------------------------------------------------
// Pairwise logits + fused max/sum reductions. One 256x256 output tile per
// block (4 a's x 4 b's). 16 waves (4M x 4N), per-wave output 64x64 = one
// (a,b) pair, computed with 32x32x16 MFMA (2x2 fragments): acc = 64 AGPR,
// live A/B frags = 16 VGPR -> fits the 64-VGPR cap of 4 waves/SIMD without
// spilling (round-5's failure). K-loop: 8 tiles of BK=64, double-buffered
// LDS, stages issued at body top and drained (vmcnt 0) at body bottom ~2000cy
// later, one barrier per tile. XCD-rectangle block swizzle.
__global__ __launch_bounds__(1024) void pairs_kernel(const ushort_t* __restrict__ Q,
                                                     const ushort_t* __restrict__ Km,
                                                     const float* __restrict__ amask,
                                                     const float* __restrict__ ls_ptr,
                                                     float* __restrict__ out) {
  __shared__ __align__(16) ushort_t lds[2 * 2 * 256 * 64];  // 128 KiB
  const int tid = threadIdx.x;
  const int wave = tid >> 6, lane = tid & 63;
  const int wr = wave >> 2, wc = wave & 3;      // 4M x 4N wave grid
  const int l31 = lane & 31, h = lane >> 5;

  const int bid = blockIdx.x;
  const int gen = bid >> 8, slot = bid & 255;
  const int xcd = slot & 7, idx = slot >> 3;
  const int by = ((gen & 1) << 4) + ((xcd >> 1) << 2) + (idx >> 3);
  const int bx = ((gen >> 1) << 4) + ((xcd & 1) << 3) + (idx & 7);

  const int l8 = lane >> 3, l7 = lane & 7;
  const int srcSlot = l7 ^ l8;

  // epilogue scalars first; drain their vmem before the pipeline
  const float lsv = expf(ls_ptr[0]);
  float amv;
  {
    float am = amask[(by * 4 + wr) * 64 + lane];
#pragma unroll
    for (int off = 1; off < 64; off <<= 1) am += __shfl_xor(am, off);
    amv = am;
  }
  VMC(0); SCHED0();

  f32x16 acc[2][2] = {};

  // per-wave stage: 8 rows (1 KiB) per call; rows wave*16+u*8
  auto SA = [&](int u, int k, int d) {
    int base = wave * 16 + u * 8;
    GLL16(Q + (size_t)(by * 256 + base + l8) * DN + k * 64 + srcSlot * 8,
          &lds[((d * 2 + 0) * 256 + base) * 64]);
  };
  auto SB = [&](int u, int k, int d) {
    int base = wave * 16 + u * 8;
    GLL16(Km + (size_t)(bx * 256 + base + l8) * DN + k * 64 + srcSlot * 8,
          &lds[((d * 2 + 1) * 256 + base) * 64]);
  };

#pragma unroll
  for (int k = 0; k < 8; ++k) {
    const int d = k & 1, dn = d ^ 1;
    const bool doST = (k < 7);
    if (k == 0) {  // prologue: stage tile 0 into buffer 0, publish
      SB(0, 0, 0); SB(1, 0, 0); SA(0, 0, 0); SA(1, 0, 0);
      VMC(0);
      BAR(); SCHED0();
    }
    // issue next tile's 4 stage loads (land-late; drained at body bottom)
    if (doST) { SB(0, k + 1, dn); SB(1, k + 1, dn); SA(0, k + 1, dn); SA(1, k + 1, dn); }
#pragma unroll
    for (int ks = 0; ks < 4; ks++) {
      bf16x8 aF[2], bF[2];
#pragma unroll
      for (int mi = 0; mi < 2; mi++) {
        int row = wr * 64 + mi * 32 + l31;
        int slt = ((ks * 2 + h) ^ (row & 7));
        aF[mi] = *(const bf16x8*)&lds[((d * 2 + 0) * 256 + row) * 64 + slt * 8];
      }
#pragma unroll
      for (int ni = 0; ni < 2; ni++) {
        int row = wc * 64 + ni * 32 + l31;
        int slt = ((ks * 2 + h) ^ (row & 7));
        bF[ni] = *(const bf16x8*)&lds[((d * 2 + 1) * 256 + row) * 64 + slt * 8];
      }
      __builtin_amdgcn_s_setprio(1);
#pragma unroll
      for (int mi = 0; mi < 2; mi++)
#pragma unroll
        for (int ni = 0; ni < 2; ni++)
          acc[mi][ni] = __builtin_amdgcn_mfma_f32_32x32x16_bf16(
              aF[mi], bF[ni], acc[mi][ni], 0, 0, 0);
      __builtin_amdgcn_s_setprio(0);
    }
    VMC(0);       // next tile's stages landed (issued ~2000 cy ago)
    BAR(); SCHED0();
  }

  // ---- fused epilogue: one (a,b) pair per wave ----
  // 32x32 C/D layout (m74/m101): col = lane&31, row = (reg&3)+8*(reg>>2)+4*(lane>>5).

  // t2v: per-row max over 64 cols, then sum over 64 rows
  float t2v = 0.f;
#pragma unroll
  for (int mi = 0; mi < 2; mi++) {
    f32x16 rm;
#pragma unroll
    for (int r = 0; r < 16; r++) rm[r] = fmaxf(acc[mi][0][r], acc[mi][1][r]);
#pragma unroll
    for (int off = 1; off < 32; off <<= 1)
#pragma unroll
      for (int r = 0; r < 16; r++) rm[r] = fmaxf(rm[r], __shfl_xor(rm[r], off));
    float s = 0.f;
#pragma unroll
    for (int r = 0; r < 16; r++) s += rm[r];
    s += __shfl_xor(s, 32);      // other half holds the other 16 rows
    t2v += s;
  }

  // v2t: per-col max over 64 rows, then sum over 64 cols
  float cm0 = -INFINITY, cm1 = -INFINITY;
#pragma unroll
  for (int mi = 0; mi < 2; mi++)
#pragma unroll
    for (int r = 0; r < 16; r++) {
      cm0 = fmaxf(cm0, acc[mi][0][r]);
      cm1 = fmaxf(cm1, acc[mi][1][r]);
    }
  cm0 = fmaxf(cm0, __shfl_xor(cm0, 32));
  cm1 = fmaxf(cm1, __shfl_xor(cm1, 32));
  float v2t = cm0 + cm1;        // cols (lane&31) and (lane&31)+32
#pragma unroll
  for (int off = 1; off < 32; off <<= 1) v2t += __shfl_xor(v2t, off);

  const int a = by * 4 + wr, b = bx * 4 + wc;
  float r = lsv * 0.5f * (t2v / amv + v2t / 64.0f);
  if (lane == 0) {
    out[a * NB + b] = r;                 // r
    out[NB * NB + b * NB + a] = r;       // r.T
  }
}

// ---------------------------------------------------------------------------
extern "C" void kernel_launch(void* const* d_in, const int* in_sizes, int n_in,
                              void* d_out, int out_size, void* d_ws, size_t ws_size,
                              hipStream_t stream) {
  const float* query = (const float*)d_in[0];
  const float* key   = (const float*)d_in[1];
  const float* amask = (const float*)d_in[2];
  const float* Wq    = (const float*)d_in[3];
  const float* bq    = (const float*)d_in[4];
  const float* Wk    = (const float*)d_in[5];
  const float* bk    = (const float*)d_in[6];
  const float* ls    = (const float*)d_in[7];

  char* ws = (char*)d_ws;
  ushort_t* Qb = (ushort_t*)(ws);                      // 8 MB
  ushort_t* Kb = (ushort_t*)(ws + 8 * 1024 * 1024);    // 8 MB

  proj_kernel<<<dim3(4, 64, 2), 256, 0, stream>>>(query, Wq, bq, Qb, key, Wk, bk, Kb);
  pairs_kernel<<<dim3(1024), 1024, 0, stream>>>(Qb, Kb, amask, ls, (float*)d_out);
}